// Round 6
// baseline (11906.229 us; speedup 1.0000x reference)
//
#include <hip/hip_runtime.h>

#define B_ 64
#define S_ 512
#define D_ 1024
#define H_ 1024
#define NBLK 128
#define NT 256
#define TB 8   // out-store batch (steps buffered in registers/scratch)

typedef __bf16 v8bf __attribute__((ext_vector_type(8)));
typedef float v4f __attribute__((ext_vector_type(4)));
typedef float f32x4 __attribute__((ext_vector_type(4)));
typedef unsigned long long u64;
typedef unsigned u32;

#define MFMA __builtin_amdgcn_mfma_f32_16x16x32_bf16

// Convert 8 consecutive f32 (32B, two float4 loads) to a bf16x8 fragment.
__device__ inline v8bf cvt8(const float* p) {
  f32x4 a = *(const f32x4*)p;
  f32x4 b = *(const f32x4*)(p + 4);
  v8bf r;
  r[0] = (__bf16)a[0]; r[1] = (__bf16)a[1]; r[2] = (__bf16)a[2]; r[3] = (__bf16)a[3];
  r[4] = (__bf16)b[0]; r[5] = (__bf16)b[1]; r[6] = (__bf16)b[2]; r[7] = (__bf16)b[3];
  return r;
}

// Persistent LSTM. ROUND 6: 128 blocks x 256 threads (was 256) -- halve the
// sync span, double per-block work. Round 5 (coalesced h + decoupled wave
// systems) confirmed the structural theory (-41%, WRITE_SIZE fell as
// predicted); remaining 13.9us/step scales with agent count (256-block
// straggler gating, 32MB/step h broadcast, 4KB flag-line hotspot) and with
// the serial per-step x-GEMM. This round:
//  - Block nb owns 8 H-cols x 4 gates = 32 n-values; weight slice 32x2048
//    bf16 = 128KB LDS (dynamic; gfx950 allows >64KB/workgroup).
//  - n-tiles = {gates 0,1 | gates 2,3}: all 4 gates of (b,hcol) land in lane
//    pairs lane^8 -> gate exchange is 8 __shfl_xor, pointwise in-register.
//  - A-fragment (x or h row) feeds BOTH n-tiles: per-lane load volume
//    unchanged while agents halve. 4 accumulators break MFMA dep chains.
//  - h tile = 1KB/block, layout [b][hcol8]; producer wave packs its 16x8
//    sub-tile via a 256B LDS buffer -> ONE contiguous 256B store (4 full
//    sectors, zero inflation). Consumer reads 16B rows, coalesced 256B/quad.
//  - Flags padded to 64B sectors (32KB region): no LLC slice hotspot.
//  - Kept from round 5: zero barriers in the loop, per-wave flag systems
//    (4 decoupled systems of 128 agents), sc1 h/flag traffic (no bulk
//    fences), s_waitcnt vmcnt(0) release, TB=8 batched NT out stores.
__global__ __launch_bounds__(NT, 1)
void lstm_persist(const float* __restrict__ x,    // (B,S,D) f32
                  const float* __restrict__ Wx,   // (4,H,D) f32
                  const float* __restrict__ Wh,   // (4,H,H) f32
                  const float* __restrict__ bias, // (4,H)   f32
                  float* __restrict__ out,        // (B,S,H) ++ (B,H) ++ (B,H), f32
                  __bf16* __restrict__ hblk,      // (2,NBLK,64,8) bf16 blocked h
                  u32* __restrict__ flags)        // [4][NBLK][16] padded flags
{
  extern __shared__ char smem[];
  v8bf*   wlds = (v8bf*)smem;              // [32 rows][256 chunks^swz] = 128KB
  __bf16* pack = (__bf16*)(smem + 131072); // [4 waves][16][8] = 1KB

  const int tid  = threadIdx.x;
  const int nb   = blockIdx.x;
  const int w    = tid >> 6;   // wave 0..3 (= wave-system id)
  const int l    = tid & 63;
  const int lm   = l & 15;     // MFMA A-row / B,D-col lane index
  const int quad = l >> 4;     // MFMA k-quad
  const int sw   = lm & 7;     // LDS swizzle key ((16+lm)&7 == lm&7)
  const int hi   = lm >> 3;    // gate-pair half within a tile
  const int hc   = lm & 7;     // local H-column

  // ---- stage weights into LDS (once), f32 -> bf16. Row nl: gate nl>>3,
  // local col nl&7; K chunks kc 0..255 (kc<128: Wx, else Wh), XOR-swizzled.
  for (int i = tid; i < 32 * 256; i += NT) {
    const int nl  = i >> 8;
    const int kc  = i & 255;
    const int g   = nl >> 3;
    const int col = (nb << 3) + (nl & 7);
    const int k   = kc << 3;
    const float* src = (k < D_)
        ? (Wx + ((size_t)(g * H_ + col) * D_ + k))
        : (Wh + ((size_t)(g * H_ + col) * H_ + (k - D_)));
    wlds[(nl << 8) + (kc ^ (nl & 7))] = cvt8(src);
  }

  const int myb = (w << 4) + lm;      // A-operand batch row this lane loads
  const int col = (nb << 3) + hc;     // H-column this lane's pointwise owns
  const float bv0 = bias[0 * H_ + col], bv1 = bias[1 * H_ + col];
  const float bv2 = bias[2 * H_ + col], bv3 = bias[3 * H_ + col];

  // pointwise ownership: batches b0,b1 = w*16 + quad*4 + (hi?{2,3}:{0,1})
  const int b0 = (w << 4) + (quad << 2) + (hi << 1);
  const int b1 = b0 + 1;

  float cr0 = 0.f, cr1 = 0.f;         // cell states (2 per lane)
  float obuf0[TB], obuf1[TB];         // batched out values

  u32* fw     = flags + (w << 11);            // my system's 128 padded flags
  u32* myflag = flags + (w << 11) + (nb << 4);

  __bf16*    mypackw = pack + (w << 7);            // my wave's 16x8 sub-tile
  const u32* mypackr = (const u32*)pack + (w << 6);

  __syncthreads();  // weights staged (only barrier in the kernel)

  for (int t = 0; t < S_; ++t) {
    v4f a00 = {0.f,0.f,0.f,0.f}, a01 = {0.f,0.f,0.f,0.f};  // tile0 (gates 0,1)
    v4f a10 = {0.f,0.f,0.f,0.f}, a11 = {0.f,0.f,0.f,0.f};  // tile1 (gates 2,3)

    // ---- x part (K = 0..1023): no dependence on h, runs before the wait ----
    const float* xrow = x + ((size_t)(myb * S_ + t)) * D_ + (quad << 3);
    #pragma unroll 4
    for (int cc = 0; cc < 16; ++cc) {
      const int c0 = cc * 2, c1 = cc * 2 + 1;
      v8bf a0 = cvt8(xrow + (c0 << 5));
      a00 = MFMA(a0, wlds[(lm << 8)        + (((c0 << 2) + quad) ^ sw)], a00, 0, 0, 0);
      a10 = MFMA(a0, wlds[((16 + lm) << 8) + (((c0 << 2) + quad) ^ sw)], a10, 0, 0, 0);
      v8bf a1 = cvt8(xrow + (c1 << 5));
      a01 = MFMA(a1, wlds[(lm << 8)        + (((c1 << 2) + quad) ^ sw)], a01, 0, 0, 0);
      a11 = MFMA(a1, wlds[((16 + lm) << 8) + (((c1 << 2) + quad) ^ sw)], a11, 0, 0, 0);
    }

    // ---- wait for my wave-system's 128 producers, then h part ----
    if (t > 0) {
      const u32 tu = (u32)t;
      for (;;) {  // lane l watches padded flags 2l, 2l+1 (64B sectors)
        const u32 f0 = __hip_atomic_load(fw + (l << 5),
            __ATOMIC_RELAXED, __HIP_MEMORY_SCOPE_AGENT);
        const u32 f1 = __hip_atomic_load(fw + (l << 5) + 16,
            __ATOMIC_RELAXED, __HIP_MEMORY_SCOPE_AGENT);
        if (__all((f0 >= tu) & (f1 >= tu))) break;
        __builtin_amdgcn_s_sleep(1);
      }
      asm volatile("" ::: "memory");  // no hoisting h loads above the poll

      // h A-frag chunk c: k = c*32 + quad*8 + j  ->  tile c*4+quad, row myb,
      // 16B contiguous. sc1 (LLC-direct) u64 loads; coalesced 256B/quad.
      const __bf16* hb = hblk + ((t & 1) ? (NBLK * 512) : 0);
      #pragma unroll 4
      for (int cc = 0; cc < 16; ++cc) {
        const int c0 = cc * 2, c1 = cc * 2 + 1;
        union { u64 q[2]; v8bf v; } h0, h1;
        const u64* ha0 = (const u64*)(hb + ((((c0 << 2) + quad) << 9) + (myb << 3)));
        const u64* ha1 = (const u64*)(hb + ((((c1 << 2) + quad) << 9) + (myb << 3)));
        h0.q[0] = __hip_atomic_load(ha0,     __ATOMIC_RELAXED, __HIP_MEMORY_SCOPE_AGENT);
        h0.q[1] = __hip_atomic_load(ha0 + 1, __ATOMIC_RELAXED, __HIP_MEMORY_SCOPE_AGENT);
        h1.q[0] = __hip_atomic_load(ha1,     __ATOMIC_RELAXED, __HIP_MEMORY_SCOPE_AGENT);
        h1.q[1] = __hip_atomic_load(ha1 + 1, __ATOMIC_RELAXED, __HIP_MEMORY_SCOPE_AGENT);
        a00 = MFMA(h0.v, wlds[(lm << 8)        + ((128 + (c0 << 2) + quad) ^ sw)], a00, 0, 0, 0);
        a10 = MFMA(h0.v, wlds[((16 + lm) << 8) + ((128 + (c0 << 2) + quad) ^ sw)], a10, 0, 0, 0);
        a01 = MFMA(h1.v, wlds[(lm << 8)        + ((128 + (c1 << 2) + quad) ^ sw)], a01, 0, 0, 0);
        a11 = MFMA(h1.v, wlds[((16 + lm) << 8) + ((128 + (c1 << 2) + quad) ^ sw)], a11, 0, 0, 0);
      }
    }

    // ---- merge parities; gate exchange via ONE lane^8 shuffle set ----
    // D layout: tile j, reg r -> (b = w*16+quad*4+r, col lm). Tile0 col lm =
    // gate hi, hcol hc; tile1 = gate 2+hi. Partner lane^8 holds the other
    // gate of each pair for the same (quad, hc).
    v4f s0 = a00 + a01;
    v4f s1 = a10 + a11;
    v4f x0, x1;
    #pragma unroll
    for (int r = 0; r < 4; ++r) {
      x0[r] = __shfl_xor(s0[r], 8, 64);
      x1[r] = __shfl_xor(s1[r], 8, 64);
    }

    float hn0, hn1;
    #pragma unroll
    for (int j = 0; j < 2; ++j) {   // my kept rows: idx = hi*2 + j
      const float vs0 = hi ? s0[2 + j] : s0[j];
      const float vx0 = hi ? x0[2 + j] : x0[j];
      const float vs1 = hi ? s1[2 + j] : s1[j];
      const float vx1 = hi ? x1[2 + j] : x1[j];
      const float g0 = (hi ? vx0 : vs0) + bv0;   // i
      const float g1 = (hi ? vs0 : vx0) + bv1;   // f
      const float g2 = (hi ? vx1 : vs1) + bv2;   // o
      const float g3 = (hi ? vs1 : vx1) + bv3;   // c_hat
      const float it = 1.f / (1.f + __expf(-g0));
      const float ft = 1.f / (1.f + __expf(-g1));
      const float ot = 1.f / (1.f + __expf(-g2));
      const float ch = 1.f - 2.f / (__expf(2.f * g3) + 1.f);  // tanh
      float& cr = (j == 0) ? cr0 : cr1;
      cr = ft * cr + it * ch;
      const float hn = ot * (1.f - 2.f / (__expf(2.f * cr) + 1.f));
      mypackw[(((quad << 2) + (hi << 1) + j) << 3) + hc] = (__bf16)hn;
      if (j == 0) hn0 = hn; else hn1 = hn;
    }

    // ---- pack -> ONE contiguous 256B store per wave (4 full sectors) ----
    asm volatile("s_waitcnt lgkmcnt(0)" ::: "memory");
    const u32 pword = mypackr[l];
    u32* dst = (u32*)(hblk + (((t + 1) & 1) ? (NBLK * 512) : 0))
               + (nb << 8) + (w << 6) + l;
    __hip_atomic_store(dst, pword, __ATOMIC_RELAXED, __HIP_MEMORY_SCOPE_AGENT);

    // ---- per-wave release: drain MY stores only, then arrive ----
    asm volatile("s_waitcnt vmcnt(0)" ::: "memory");
    __hip_atomic_store(myflag, (u32)(t + 1), __ATOMIC_RELAXED,
                       __HIP_MEMORY_SCOPE_AGENT);

    // ---- batched out stores (after the release; ~TB steps to drain) ----
    obuf0[t & (TB - 1)] = hn0;
    obuf1[t & (TB - 1)] = hn1;
    if ((t & (TB - 1)) == TB - 1) {
      #pragma unroll
      for (int i = 0; i < TB; ++i) {
        const int ts = t - TB + 1 + i;
        __builtin_nontemporal_store(
            obuf0[i], &out[((size_t)(b0 * S_ + ts)) * H_ + col]);
        __builtin_nontemporal_store(
            obuf1[i], &out[((size_t)(b1 * S_ + ts)) * H_ + col]);
      }
    }
    if (t == S_ - 1) {
      const size_t base = (size_t)B_ * S_ * H_;
      __builtin_nontemporal_store(hn0, &out[base + (size_t)b0 * H_ + col]);
      __builtin_nontemporal_store(hn1, &out[base + (size_t)b1 * H_ + col]);
      __builtin_nontemporal_store(cr0, &out[base + (size_t)(B_ * H_) + (size_t)b0 * H_ + col]);
      __builtin_nontemporal_store(cr1, &out[base + (size_t)(B_ * H_) + (size_t)b1 * H_ + col]);
    }
  }
}

extern "C" void kernel_launch(void* const* d_in, const int* in_sizes, int n_in,
                              void* d_out, int out_size, void* d_ws, size_t ws_size,
                              hipStream_t stream) {
  const float* x    = (const float*)d_in[0];
  const float* Wx   = (const float*)d_in[1];
  const float* Wh   = (const float*)d_in[2];
  const float* bias = (const float*)d_in[3];
  float* out = (float*)d_out;

  u32*    flags = (u32*)d_ws;                    // 4*128*64B = 32KB padded
  __bf16* hblk  = (__bf16*)((char*)d_ws + 32768); // 2*128*512 bf16 = 256KB

  // ws is poisoned 0xAA before every timed launch: zero the flag region.
  hipMemsetAsync(d_ws, 0, 32768, stream);

  lstm_persist<<<dim3(NBLK), dim3(NT), 131072 + 1024, stream>>>(
      x, Wx, Wh, bias, out, hblk, flags);
}

// Round 7
// 6730.893 us; speedup vs baseline: 1.7689x; 1.7689x over previous
//
#include <hip/hip_runtime.h>

#define B_ 64
#define S_ 512
#define D_ 1024
#define H_ 1024
#define NBLK 256
#define NT 512
#define TB 8      // out-store batch (steps buffered in registers)
#define NSLOT 4   // x->h LDS ring depth (steps of x-wave lead)

typedef __bf16 v8bf __attribute__((ext_vector_type(8)));
typedef float v4f __attribute__((ext_vector_type(4)));
typedef float f32x4 __attribute__((ext_vector_type(4)));
typedef unsigned long long u64;
typedef unsigned u32;

#define MFMA __builtin_amdgcn_mfma_f32_16x16x32_bf16

// Convert 8 consecutive f32 (32B, two float4 loads) to a bf16x8 fragment.
__device__ inline v8bf cvt8(const float* p) {
  f32x4 a = *(const f32x4*)p;
  f32x4 b = *(const f32x4*)(p + 4);
  v8bf r;
  r[0] = (__bf16)a[0]; r[1] = (__bf16)a[1]; r[2] = (__bf16)a[2]; r[3] = (__bf16)a[3];
  r[4] = (__bf16)b[0]; r[5] = (__bf16)b[1]; r[6] = (__bf16)b[2]; r[7] = (__bf16)b[3];
  return r;
}

// Persistent LSTM. ROUND 7: wave specialization. Rounds 0-6 established:
// barrier protocol ~neutral, fences ~neutral, prefetch ~neutral, agent-count
// scaling BACKWARDS (r6) -- per-step time = per-block serial stream at ~37
// cy/instruction (1 wave/SIMD: zero TLP, all latency exposed) + ~4.5us sync
// chain. Fix: r5's exact geometry (256 blocks, N=16/block, r5 h-layout +
// flag protocol) but 512 threads = 8 waves (2/SIMD), K split on the x/h
// boundary across wave pairs:
//   x-wave w (0-3):  K 0..1023 (x-GEMM) for batch rows w*16+lm. No global
//     sync; runs up to NSLOT steps ahead; hands v4f partials to partner via
//     LDS ring xacc[slot][w][lane] with workgroup-scope seq flags.
//   h-wave s (4-7):  consume xacc (frees slot early) -> global flag poll ->
//     h-gather (sc1 LLC) + 32 MFMAs -> shuffle exchange -> pointwise ->
//     r5 h-store -> vmcnt(0) -> flag -> TB-batched NT out stores.
// Each SIMD gets one x-wave + one h-wave: stalls of one are issue slots for
// the other; the recurrent chain no longer contains the x stream at all.
__global__ __launch_bounds__(NT, 2)
void lstm_persist(const float* __restrict__ x,    // (B,S,D) f32
                  const float* __restrict__ Wx,   // (4,H,D) f32
                  const float* __restrict__ Wh,   // (4,H,H) f32
                  const float* __restrict__ bias, // (4,H)   f32
                  float* __restrict__ out,        // (B,S,H) ++ (B,H) ++ (B,H), f32
                  __bf16* __restrict__ hblk,      // (2,NBLK,64,4) bf16 blocked h
                  u32* __restrict__ flags)        // [4][NBLK] per-system flags
{
  extern __shared__ char smem[];
  v8bf* wlds = (v8bf*)smem;                    // [16 rows][256 chunks^swz] 64KB
  v4f*  xacc = (v4f*)(smem + 65536);           // [NSLOT][4][64] v4f = 16KB
  u32*  seq  = (u32*)(smem + 65536 + 16384);   // xseq[4*16] ++ hseq[4*16]

  const int tid  = threadIdx.x;
  const int nb   = blockIdx.x;
  const int w8   = tid >> 6;   // 0..7: 0-3 x-waves, 4-7 h-waves
  const int l    = tid & 63;
  const int lm   = l & 15;     // MFMA A-row / B,D-col lane index
  const int quad = l >> 4;     // MFMA k-quad
  const int sw   = lm & 7;     // LDS swizzle key

  // ---- stage weights into LDS (once), f32 -> bf16 (all 8 waves) ----
  for (int i = tid; i < 16 * 256; i += NT) {
    const int nl  = i >> 8;          // 0..15: gate g = nl>>2, local col = nl&3
    const int kc  = i & 255;         // 8-elt chunk index along K (k = kc*8)
    const int g   = nl >> 2;
    const int col = (nb << 2) + (nl & 3);
    const int k   = kc << 3;
    const float* src = (k < D_)
        ? (Wx + ((size_t)(g * H_ + col) * D_ + k))
        : (Wh + ((size_t)(g * H_ + col) * H_ + (k - D_)));
    wlds[(nl << 8) + (kc ^ (nl & 7))] = cvt8(src);
  }
  if (tid < 128) seq[tid] = 0;   // xseq + hseq zeroed

  __syncthreads();  // weights staged + seq init (only barrier in the kernel)

  u32* xseq = seq;        // [w*16] (64B-padded)
  u32* hseq = seq + 64;   // [s*16]

  if (w8 < 4) {
    // ================= x-wave: K 0..1023, no global sync =================
    const int w   = w8;
    const int myb = (w << 4) + lm;
    for (int t = 0; t < S_; ++t) {
      if (t >= NSLOT) {  // slot credit: partner consumed slot from t-NSLOT
        while (__hip_atomic_load(&hseq[w << 4], __ATOMIC_ACQUIRE,
                                 __HIP_MEMORY_SCOPE_WORKGROUP)
               < (u32)(t - NSLOT + 1)) {
          __builtin_amdgcn_s_sleep(1);
        }
      }
      v4f a0 = {0.f,0.f,0.f,0.f}, a1 = {0.f,0.f,0.f,0.f};
      const float* xrow = x + ((size_t)(myb * S_ + t)) * D_ + (quad << 3);
      #pragma unroll 4
      for (int cc = 0; cc < 16; ++cc) {
        const int c0 = cc * 2, c1 = cc * 2 + 1;
        v8bf f0 = cvt8(xrow + (c0 << 5));
        a0 = MFMA(f0, wlds[(lm << 8) + (((c0 << 2) + quad) ^ sw)], a0, 0, 0, 0);
        v8bf f1 = cvt8(xrow + (c1 << 5));
        a1 = MFMA(f1, wlds[(lm << 8) + (((c1 << 2) + quad) ^ sw)], a1, 0, 0, 0);
      }
      xacc[((t & (NSLOT - 1)) << 8) + (w << 6) + l] = a0 + a1;
      asm volatile("s_waitcnt lgkmcnt(0)" ::: "memory");  // ring write landed
      if (l == 0)
        __hip_atomic_store(&xseq[w << 4], (u32)(t + 1), __ATOMIC_RELEASE,
                           __HIP_MEMORY_SCOPE_WORKGROUP);
    }
  } else {
    // ================= h-wave: K 1024..2047 + recurrence =================
    const int s     = w8 & 3;          // wave-system id (= partner x-wave)
    const int myb   = (s << 4) + lm;   // batch row this lane owns
    const int myb4  = myb << 2;
    const int mycol = (nb << 2) + quad;
    float bv[4];
    #pragma unroll
    for (int g = 0; g < 4; ++g) bv[g] = bias[g * H_ + mycol];

    float c_reg = 0.f;
    float obuf[TB];

    const u32* fw     = flags + (s << 8);       // my system's 256 flags
    u32*       myflag = flags + (s << 8) + nb;

    for (int t = 0; t < S_; ++t) {
      // ---- 1. consume partner's x partial (frees ring slot early) ----
      while (__hip_atomic_load(&xseq[s << 4], __ATOMIC_ACQUIRE,
                               __HIP_MEMORY_SCOPE_WORKGROUP) < (u32)(t + 1)) {
        __builtin_amdgcn_s_sleep(1);
      }
      const v4f xa = xacc[((t & (NSLOT - 1)) << 8) + (s << 6) + l];
      asm volatile("s_waitcnt lgkmcnt(0)" ::: "memory");  // xa in registers
      if (l == 0)
        __hip_atomic_store(&hseq[s << 4], (u32)(t + 1), __ATOMIC_RELEASE,
                           __HIP_MEMORY_SCOPE_WORKGROUP);

      v4f acc0 = xa, acc1 = {0.f,0.f,0.f,0.f};

      // ---- 2. wait for my system's 256 producers, then h-GEMM ----
      if (t > 0) {
        const u32 tu = (u32)t;
        for (;;) {  // lane l watches fw[4l..4l+3]: coalesced 1KB across wave
          const u32 f0 = __hip_atomic_load(fw + (l << 2) + 0,
              __ATOMIC_RELAXED, __HIP_MEMORY_SCOPE_AGENT);
          const u32 f1 = __hip_atomic_load(fw + (l << 2) + 1,
              __ATOMIC_RELAXED, __HIP_MEMORY_SCOPE_AGENT);
          const u32 f2 = __hip_atomic_load(fw + (l << 2) + 2,
              __ATOMIC_RELAXED, __HIP_MEMORY_SCOPE_AGENT);
          const u32 f3 = __hip_atomic_load(fw + (l << 2) + 3,
              __ATOMIC_RELAXED, __HIP_MEMORY_SCOPE_AGENT);
          if (__all((f0 >= tu) & (f1 >= tu) & (f2 >= tu) & (f3 >= tu))) break;
          __builtin_amdgcn_s_sleep(1);
        }
        asm volatile("" ::: "memory");  // no hoisting h loads above the poll

        // h A-frag chunk c: k = c*32+quad*8+j -> blocks j0=2*quad+8c, j0+1;
        // 8B each at [block][myb*4]. sc1 (LLC-direct) u64 loads.
        const __bf16* hb = hblk + ((t & 1) ? (1 << 16) : 0);
        #pragma unroll 4
        for (int cc = 0; cc < 16; ++cc) {
          const int c0 = cc * 2, c1 = cc * 2 + 1;
          const int j0 = (quad << 1) + (c0 << 3);
          const int j1 = (quad << 1) + (c1 << 3);
          union { u64 q[2]; v8bf v; } h0, h1;
          h0.q[0] = __hip_atomic_load((const u64*)(hb + (j0 << 8) + myb4),
              __ATOMIC_RELAXED, __HIP_MEMORY_SCOPE_AGENT);
          h0.q[1] = __hip_atomic_load((const u64*)(hb + ((j0 + 1) << 8) + myb4),
              __ATOMIC_RELAXED, __HIP_MEMORY_SCOPE_AGENT);
          h1.q[0] = __hip_atomic_load((const u64*)(hb + (j1 << 8) + myb4),
              __ATOMIC_RELAXED, __HIP_MEMORY_SCOPE_AGENT);
          h1.q[1] = __hip_atomic_load((const u64*)(hb + ((j1 + 1) << 8) + myb4),
              __ATOMIC_RELAXED, __HIP_MEMORY_SCOPE_AGENT);
          acc0 = MFMA(h0.v, wlds[(lm << 8) + ((128 + (c0 << 2) + quad) ^ sw)], acc0, 0, 0, 0);
          acc1 = MFMA(h1.v, wlds[(lm << 8) + ((128 + (c1 << 2) + quad) ^ sw)], acc1, 0, 0, 0);
        }
      }

      v4f accs = acc0 + acc1;

      // ---- gate exchange: D layout row m=quad*4+r (batch), col n=lm.
      // Dest lane (b=16s+lm, c=quad) needs cols {g*4+quad} at row lm. ----
      float gv[4];
      const int rsel = lm & 3;
      #pragma unroll
      for (int g = 0; g < 4; ++g) {
        const int srcl = ((lm >> 2) << 4) + (g << 2) + quad;
        float t0 = __shfl(accs[0], srcl, 64);
        float t1 = __shfl(accs[1], srcl, 64);
        float t2 = __shfl(accs[2], srcl, 64);
        float t3 = __shfl(accs[3], srcl, 64);
        gv[g] = (rsel == 0 ? t0 : rsel == 1 ? t1 : rsel == 2 ? t2 : t3) + bv[g];
      }

      // ---- LSTM pointwise (fp32) ----
      const float it = 1.f / (1.f + __expf(-gv[0]));
      const float ft = 1.f / (1.f + __expf(-gv[1]));
      const float ot = 1.f / (1.f + __expf(-gv[2]));
      const float ch = 1.f - 2.f / (__expf(2.f * gv[3]) + 1.f);  // tanh
      c_reg = ft * c_reg + it * ch;
      const float hn = ot * (1.f - 2.f / (__expf(2.f * c_reg) + 1.f));

      // ---- blocked h store (r5): wave writes 128B contiguous ----
      {
        union { __bf16 b; unsigned short u; } hb2;
        hb2.b = (__bf16)hn;
        __hip_atomic_store(
            (unsigned short*)(hblk + (((t + 1) & 1) ? (1 << 16) : 0)
                              + (nb << 8) + myb4 + quad),
            hb2.u, __ATOMIC_RELAXED, __HIP_MEMORY_SCOPE_AGENT);
      }

      // ---- per-wave release: drain MY stores only, then arrive ----
      asm volatile("s_waitcnt vmcnt(0)" ::: "memory");
      __hip_atomic_store(myflag, (u32)(t + 1), __ATOMIC_RELAXED,
                         __HIP_MEMORY_SCOPE_AGENT);

      // ---- batched out stores (after the release; ~TB steps to drain) ----
      obuf[t & (TB - 1)] = hn;
      if ((t & (TB - 1)) == TB - 1) {
        #pragma unroll
        for (int i = 0; i < TB; ++i)
          __builtin_nontemporal_store(
              obuf[i], &out[((size_t)(myb * S_ + (t - TB + 1 + i))) * H_ + mycol]);
      }
      if (t == S_ - 1) {
        __builtin_nontemporal_store(
            hn, &out[(size_t)B_ * S_ * H_ + (size_t)myb * H_ + mycol]);   // h_last
        __builtin_nontemporal_store(
            c_reg, &out[(size_t)B_ * S_ * H_ + (size_t)(B_ * H_)
                        + (size_t)myb * H_ + mycol]);                      // c_last
      }
    }
  }
}

extern "C" void kernel_launch(void* const* d_in, const int* in_sizes, int n_in,
                              void* d_out, int out_size, void* d_ws, size_t ws_size,
                              hipStream_t stream) {
  const float* x    = (const float*)d_in[0];
  const float* Wx   = (const float*)d_in[1];
  const float* Wh   = (const float*)d_in[2];
  const float* bias = (const float*)d_in[3];
  float* out = (float*)d_out;

  u32*    flags = (u32*)d_ws;                    // 4*NBLK*4B = 4KB region
  __bf16* hblk  = (__bf16*)((char*)d_ws + 4096); // 2*256*256 bf16 = 256KB

  // ws is poisoned 0xAA before every timed launch: zero the flag region.
  hipMemsetAsync(d_ws, 0, 4096, stream);

  const size_t lds_bytes = 65536 + NSLOT * 4 * 64 * 16 + 512;  // 82432
  lstm_persist<<<dim3(NBLK), dim3(NT), lds_bytes, stream>>>(
      x, Wx, Wh, bias, out, hblk, flags);
}